// Round 14
// baseline (495.158 us; speedup 1.0000x reference)
//
#include <hip/hip_runtime.h>
#include <math.h>

#define BB 32
#define SS 2048
#define HH 1024
#define MT (BB*SS)      // 65536 rows

#define BM 256
#define BN 256
#define BK 32           // fp32 k per tile (hi/lo bf16 planes)
#define NT (HH/BK)      // 32 k-tiles
#define NCH (HH/BN)     // 4 n-chunks
#define THREADS 512
// B_pre per (nch,kt) tile: 2 planes x 8 nfrags x 2 ksteps x 512 u16 = 16384 (32KB)
#define BTILE 16384

typedef float  f32x16 __attribute__((ext_vector_type(16)));
typedef short  s16x8  __attribute__((ext_vector_type(8)));
typedef unsigned short u16;

// truncation split: x ~= hi + lo, |x - hi - lo| <= 2^-16 |x|
__device__ inline void split1(float x, u16& h, u16& l) {
    unsigned u = __float_as_uint(x);
    h = (u16)(u >> 16);
    float hf = __uint_as_float((u >> 16) << 16);
    l = (u16)(__float_as_uint(x - hf) >> 16);
}
__device__ inline void split8v(float4 v0, float4 v1, s16x8& h, s16x8& l) {
    float x[8] = {v0.x,v0.y,v0.z,v0.w,v1.x,v1.y,v1.z,v1.w};
    #pragma unroll
    for (int j = 0; j < 8; ++j) {
        u16 hh, ll; split1(x[j], hh, ll);
        h[j] = (short)hh; l[j] = (short)ll;
    }
}

// async global->LDS, 16B per lane; lds dest wave-uniform base + lane*16
__device__ __forceinline__ void gload16(const u16* g, u16* l) {
    __builtin_amdgcn_global_load_lds(
        (const __attribute__((address_space(1))) unsigned int*)g,
        (__attribute__((address_space(3))) unsigned int*)l, 16, 0, 0);
}

// ---------------- Kernel 1: dec_proj[b][n] = dh[b]·Wa_w[:,n] + Wa_b[n] + Ua_b[n]
__global__ void dec_proj_kernel(const float* __restrict__ dh,
                                const float* __restrict__ Wa_w,
                                const float* __restrict__ Wa_b,
                                const float* __restrict__ Ua_b,
                                float* __restrict__ dec_proj) {
    __shared__ float sdh[HH];
    const int b   = blockIdx.x;
    const int nq  = blockIdx.y;           // 0..3
    const int tid = threadIdx.x;          // 256
    for (int i = tid; i < HH; i += 256) sdh[i] = dh[b*HH + i];
    __syncthreads();
    const int n = nq*256 + tid;
    float acc = Wa_b[n] + Ua_b[n];
    for (int k = 0; k < HH; ++k)
        acc = fmaf(sdh[k], Wa_w[(size_t)k*HH + n], acc);
    dec_proj[b*HH + n] = acc;
}

// ---------------- Kernel 2: Ua [K][N] -> B_pre split-bf16 image for 32x32x16
// LANE-MAJOR frag groups: B_pre[(nch*NT+kt)*16384 + plane*8192 + nf*1024
//                               + ks*512 + (ch*32 + col)*8 + j]
//   n = nch*256 + nf*32 + col ; k = kt*32 + ks*16 + ch*8 + j ; plane 0=hi,1=lo
// Lane l reads its 8 u16 at frag_base + l*8 (contiguous 1KB wave read):
//   l -> (ch=l>>5, col=l&31)  =>  B[col=l&31][k-chunk=l>>5]  (r13-verified map)
__global__ void transpose_convert_kernel(const float* __restrict__ Ua,
                                         u16* __restrict__ B_pre) {
    __shared__ u16 shh[64][72], shl[64][72];
    const int nb = blockIdx.x * 64, kb = blockIdx.y * 64;
    const int tid = threadIdx.x;          // 256
    const int kl = tid >> 4, nl4 = (tid & 15) * 4;
    #pragma unroll
    for (int q = 0; q < 4; ++q) {
        const int k = kl + q*16;
        float4 v = *(const float4*)&Ua[(size_t)(kb + k)*HH + nb + nl4];
        float x[4] = {v.x, v.y, v.z, v.w};
        #pragma unroll
        for (int j = 0; j < 4; ++j) {
            u16 hh, ll; split1(x[j], hh, ll);
            shh[k][nl4 + j] = hh; shl[k][nl4 + j] = ll;
        }
    }
    __syncthreads();
    const int nl = tid >> 3, kc8 = (tid & 7) * 8;
    #pragma unroll
    for (int q = 0; q < 2; ++q) {
        const int n = nb + nl + q*32;
        const int kglob = kb + kc8;
        s16x8 hv, lv;
        #pragma unroll
        for (int j = 0; j < 8; ++j) {
            hv[j] = (short)shh[kc8 + j][nl + q*32];
            lv[j] = (short)shl[kc8 + j][nl + q*32];
        }
        const int nchI = n >> 8, nfI = (n >> 5) & 7, colr = n & 31;
        const int ktI = kglob >> 5, ksI = (kglob >> 4) & 1, chI = (kglob >> 3) & 1;
        const size_t base = (size_t)(nchI*NT + ktI) * BTILE;
        const size_t idxH = base + nfI*1024 + ksI*512 + (chI*32 + colr)*8;
        *(s16x8*)&B_pre[idxH]        = hv;
        *(s16x8*)&B_pre[idxH + 8192] = lv;
    }
}

// ---------------- Kernel 3: free-run split-bf16 3-product MFMA GEMM, 32x32x16
// r11 schedule (best measured): gloadB(j+1) at top + sched_barrier; compute;
// writeA(j+1)+loadA(j+2) at end; ONE __syncthreads per tile.
// vs r13: frag groups are LANE-MAJOR on both write and read -> every frag
// ds_read_b128 is base + lane*8 u16 = contiguous 1KB (0-conflict); A staging
// ds_write stays linear at tid*16B (0-conflict). r13's lc*16+lh*8 read
// pattern was an 8-way bank conflict (2.5e7 counted) - the regression cause.
// A image per buf: [mfrag8][kstep2][(chunk2 x row32) lane-major x 8] u16.
__global__ __launch_bounds__(THREADS, 1)
void gemm_fr_kernel(const float* __restrict__ A,        // enc [M, K] fp32
                    const u16* __restrict__ B_pre,      // split image (lane-major)
                    const float* __restrict__ dec_proj, // [B, H] (biases folded)
                    const float* __restrict__ Va_w,     // [H]
                    float* __restrict__ partials)       // [M, 16]
{
    __shared__ __align__(16) u16 AhS[2][BM*BK];   // 2 x 16KB
    __shared__ __align__(16) u16 AlS[2][BM*BK];   // 2 x 16KB
    __shared__ __align__(16) u16 BS[2][BTILE];    // 2 x 32KB

    // XCD-chunked bijective swizzle: 1024 blocks, 128 per XCD;
    // nch fastest -> 4 concurrent blocks share each A panel via L2.
    const int bid = blockIdx.x;
    const int wg  = (bid & 7) * 128 + (bid >> 3);
    const int nch = wg & 3;
    const int mt  = wg >> 2;
    const int m0  = mt * BM, n0 = nch * BN;

    const int tid = threadIdx.x, lane = tid & 63, wid = tid >> 6;
    const int wm = wid >> 2, wn = wid & 3;    // 2 x 4 waves, per-wave 128x64
    const int lc = lane & 31, lh = lane >> 5; // 32x32 operand coords

    // A staging: thread covers elems eid = tid and tid+512 (8 fp32 each).
    // eid -> mfrag=eid>>7, kstep=(eid>>6)&1, chunk=(eid>>5)&1, row=eid&31
    // global row = m0 + mfrag*32 + row ; k-off = kstep*16 + chunk*8
    const int e0 = tid, e1 = tid + 512;
    const float* Ab0 = A + (size_t)(m0 + (e0>>7)*32 + (e0&31))*HH
                         + ((e0>>6)&1)*16 + ((e0>>5)&1)*8;
    const float* Ab1 = A + (size_t)(m0 + (e1>>7)*32 + (e1&31))*HH
                         + ((e1>>6)&1)*16 + ((e1>>5)&1)*8;
    // LDS dests: linear -> zero conflicts
    const int aw0 = tid*8, aw1 = tid*8 + 4096;   // u16 units
    // B staging: wave wid DMAs 4 x 1KB chunks of the 32KB tile image
    const u16* Btile = B_pre + (size_t)nch*NT*BTILE + wid*2048 + lane*8;

    f32x16 acc[4][2];
    #pragma unroll
    for (int i = 0; i < 4; ++i)
        #pragma unroll
        for (int j = 0; j < 2; ++j)
            #pragma unroll
            for (int r = 0; r < 16; ++r) acc[i][j][r] = 0.f;

    s16x8  bh[2][2], bl[2][2];    // B frags [nf][ks], read once per tile (32 VGPR)
    float4 a0_, a1_, a2_, a3_;    // A staging regs (16 VGPR)

    auto gloadB = [&](int kt, int db) {
        const u16* src = Btile + (size_t)kt*BTILE;
        u16* dst = &BS[db][wid*2048];
        gload16(src,        dst);
        gload16(src +  512, dst +  512);
        gload16(src + 1024, dst + 1024);
        gload16(src + 1536, dst + 1536);
    };
    auto loadA = [&](int kt) {
        const float* p0 = Ab0 + kt*BK;
        const float* p1 = Ab1 + kt*BK;
        a0_ = *(const float4*)(p0 + 0);
        a1_ = *(const float4*)(p0 + 4);
        a2_ = *(const float4*)(p1 + 0);
        a3_ = *(const float4*)(p1 + 4);
    };
    auto writeA = [&](int db) {
        s16x8 h, l;
        split8v(a0_, a1_, h, l);
        *(s16x8*)&AhS[db][aw0] = h; *(s16x8*)&AlS[db][aw0] = l;
        split8v(a2_, a3_, h, l);
        *(s16x8*)&AhS[db][aw1] = h; *(s16x8*)&AlS[db][aw1] = l;
    };
    auto readB = [&](int cb) {
        #pragma unroll
        for (int nf = 0; nf < 2; ++nf)
            #pragma unroll
            for (int ks = 0; ks < 2; ++ks) {
                const int off = (wn*2 + nf)*1024 + ks*512 + lane*8;  // 1KB contiguous
                bh[nf][ks] = *(const s16x8*)&BS[cb][off];
                bl[nf][ks] = *(const s16x8*)&BS[cb][8192 + off];
            }
    };

    // prologue: stage tile 0 into buf 0
    loadA(0);
    gloadB(0, 0);
    writeA(0);
    __syncthreads();
    loadA(1);   // A(1) regs held through iter 0

    for (int j = 0; j < NT; ++j) {
        const int cb = j & 1;
        const bool hn = (j + 1 < NT);
        if (hn) gloadB(j + 1, cb ^ 1);     // B DMA for next tile, issued early
        __builtin_amdgcn_sched_barrier(0);

        readB(cb);
        s16x8 ahp[2][2], alp[2][2];        // A frags [pp][ks], 1-mfrag pipeline
        #pragma unroll
        for (int ks = 0; ks < 2; ++ks) {
            const int o = (wm*4 + 0)*1024 + ks*512 + lane*8;
            ahp[0][ks] = *(const s16x8*)&AhS[cb][o];
            alp[0][ks] = *(const s16x8*)&AlS[cb][o];
        }
        #pragma unroll
        for (int mf = 0; mf < 4; ++mf) {
            if (mf < 3) {
                #pragma unroll
                for (int ks = 0; ks < 2; ++ks) {
                    const int o = (wm*4 + mf + 1)*1024 + ks*512 + lane*8;
                    ahp[(mf+1)&1][ks] = *(const s16x8*)&AhS[cb][o];
                    alp[(mf+1)&1][ks] = *(const s16x8*)&AlS[cb][o];
                }
            }
            __builtin_amdgcn_s_setprio(1);
            #pragma unroll
            for (int nf = 0; nf < 2; ++nf) {
                f32x16 c = acc[mf][nf];
                #pragma unroll
                for (int ks = 0; ks < 2; ++ks) {
                    c = __builtin_amdgcn_mfma_f32_32x32x16_bf16(ahp[mf&1][ks], bh[nf][ks], c, 0, 0, 0);
                    c = __builtin_amdgcn_mfma_f32_32x32x16_bf16(ahp[mf&1][ks], bl[nf][ks], c, 0, 0, 0);
                    c = __builtin_amdgcn_mfma_f32_32x32x16_bf16(alp[mf&1][ks], bh[nf][ks], c, 0, 0, 0);
                }
                acc[mf][nf] = c;
            }
            __builtin_amdgcn_s_setprio(0);
        }
        // staging at END (r11 proven order)
        if (hn) {
            writeA(cb ^ 1);
            loadA(j + 2 < NT ? j + 2 : j + 1);
        }
        __syncthreads();
    }

    // epilogue: rowsum over this wave's 64 n-cols of Va[n]*tanh(C+dp[n])
    // 32x32 C layout (verified m74/m101): col=lane&31, row=(r&3)+8*(r>>2)+4*(lane>>5)
    const int bidx = m0 >> 11;            // batch index (2048 rows per batch)
    float dp2[2], va2[2];
    #pragma unroll
    for (int nf = 0; nf < 2; ++nf) {
        const int n = n0 + wn*64 + nf*32 + lc;
        dp2[nf] = dec_proj[bidx*HH + n];
        va2[nf] = Va_w[n];
    }
    #pragma unroll
    for (int mf = 0; mf < 4; ++mf) {
        #pragma unroll
        for (int r = 0; r < 16; ++r) {
            float s = va2[0] * tanhf(acc[mf][0][r] + dp2[0])
                    + va2[1] * tanhf(acc[mf][1][r] + dp2[1]);
            s += __shfl_xor(s, 1, 64);
            s += __shfl_xor(s, 2, 64);
            s += __shfl_xor(s, 4, 64);
            s += __shfl_xor(s, 8, 64);
            s += __shfl_xor(s, 16, 64);
            if (lc == 0) {
                const int m = m0 + wm*128 + mf*32 + (r & 3) + 8*(r >> 2) + 4*lh;
                partials[(size_t)m*16 + nch*4 + wn] = s;
            }
        }
    }
}

// ---------------- Kernel 4: sum 16 partials + Va_b, mask, softmax over S
__global__ void softmax_kernel(const float* __restrict__ partials,
                               const int* __restrict__ mask,
                               const float* __restrict__ vb_ptr,
                               float* __restrict__ out)
{
    const int b   = blockIdx.x;
    const int tid = threadIdx.x;   // 256, each handles 8 s-positions
    __shared__ float sred[8];
    const float vb = vb_ptr[0];
    float sc[8];
    float mymax = -INFINITY;
    #pragma unroll
    for (int i = 0; i < 8; ++i) {
        const int s = i*256 + tid;
        const float4* p = (const float4*)&partials[((size_t)b*SS + s)*16];
        const float4 x = p[0], y = p[1], z = p[2], w = p[3];
        float v = (((x.x+x.y)+(x.z+x.w)) + ((y.x+y.y)+(y.z+y.w)))
                + (((z.x+z.y)+(z.z+z.w)) + ((w.x+w.y)+(w.z+w.w))) + vb;
        if (mask[b*SS + s] == 0) v = -1e9f;
        sc[i] = v;
        mymax = fmaxf(mymax, v);
    }
    #pragma unroll
    for (int off = 1; off < 64; off <<= 1)
        mymax = fmaxf(mymax, __shfl_xor(mymax, off, 64));
    const int wave = tid >> 6, lane = tid & 63;
    if (lane == 0) sred[wave] = mymax;
    __syncthreads();
    const float bmax = fmaxf(fmaxf(sred[0], sred[1]), fmaxf(sred[2], sred[3]));
    float ex[8], mysum = 0.f;
    #pragma unroll
    for (int i = 0; i < 8; ++i) {
        ex[i] = __expf(sc[i] - bmax);
        mysum += ex[i];
    }
    #pragma unroll
    for (int off = 1; off < 64; off <<= 1)
        mysum += __shfl_xor(mysum, off, 64);
    if (lane == 0) sred[4 + wave] = mysum;
    __syncthreads();
    const float inv = 1.f / (sred[4] + sred[5] + sred[6] + sred[7]);
    #pragma unroll
    for (int i = 0; i < 8; ++i)
        out[(size_t)b*SS + i*256 + tid] = ex[i] * inv;
}

extern "C" void kernel_launch(void* const* d_in, const int* in_sizes, int n_in,
                              void* d_out, int out_size, void* d_ws, size_t ws_size,
                              hipStream_t stream) {
    const float* dh   = (const float*)d_in[0];
    const float* enc  = (const float*)d_in[1];
    const int*   mask = (const int*)d_in[2];
    const float* Wa_w = (const float*)d_in[3];
    const float* Wa_b = (const float*)d_in[4];
    const float* Ua_w = (const float*)d_in[5];
    const float* Ua_b = (const float*)d_in[6];
    const float* Va_w = (const float*)d_in[7];
    const float* Va_b = (const float*)d_in[8];
    float* out = (float*)d_out;

    float* dec_proj = (float*)d_ws;                       // [B,H]    128 KB
    float* partials = dec_proj + BB*HH;                   // [M,16]   4 MB
    u16*   B_pre    = (u16*)(partials + (size_t)MT*16);   // split image, 4 MB

    dec_proj_kernel<<<dim3(BB, 4), 256, 0, stream>>>(dh, Wa_w, Wa_b, Ua_b, dec_proj);
    transpose_convert_kernel<<<dim3(HH/64, HH/64), 256, 0, stream>>>(Ua_w, B_pre);
    gemm_fr_kernel<<<(MT/BM)*NCH, THREADS, 0, stream>>>(enc, B_pre, dec_proj, Va_w, partials);
    softmax_kernel<<<BB, 256, 0, stream>>>(partials, mask, Va_b, out);
}

// Round 15
// 392.743 us; speedup vs baseline: 1.2608x; 1.2608x over previous
//
#include <hip/hip_runtime.h>
#include <math.h>

#define BB 32
#define SS 2048
#define HH 1024
#define MT (BB*SS)      // 65536 rows

#define BM 256
#define BN 256
#define BK 32           // fp32 k per tile (hi/lo bf16 planes)
#define NT (HH/BK)      // 32 k-tiles
#define NCH (HH/BN)     // 4 n-chunks
#define THREADS 1024    // 16 waves (4m x 4n), per-wave 64x64 -> 4 waves/SIMD
// B_pre per (nch,kt) tile: 2 planes x 16 frags x 512 u16 = 16384 u16 (32KB)
#define BTILE 16384

typedef float  f32x4 __attribute__((ext_vector_type(4)));
typedef short  s16x8 __attribute__((ext_vector_type(8)));
typedef unsigned short u16;

// truncation split: x ~= hi + lo, |x - hi - lo| <= 2^-16 |x|
__device__ inline void split1(float x, u16& h, u16& l) {
    unsigned u = __float_as_uint(x);
    h = (u16)(u >> 16);
    float hf = __uint_as_float((u >> 16) << 16);
    l = (u16)(__float_as_uint(x - hf) >> 16);
}
__device__ inline void split8v(float4 v0, float4 v1, s16x8& h, s16x8& l) {
    float x[8] = {v0.x,v0.y,v0.z,v0.w,v1.x,v1.y,v1.z,v1.w};
    #pragma unroll
    for (int j = 0; j < 8; ++j) {
        u16 hh, ll; split1(x[j], hh, ll);
        h[j] = (short)hh; l[j] = (short)ll;
    }
}

// async global->LDS, 16B per lane; lds dest wave-uniform base + lane*16
__device__ __forceinline__ void gload16(const u16* g, u16* l) {
    __builtin_amdgcn_global_load_lds(
        (const __attribute__((address_space(1))) unsigned int*)g,
        (__attribute__((address_space(3))) unsigned int*)l, 16, 0, 0);
}

// ---------------- Kernel 1: dec_proj[b][n] = dh[b]·Wa_w[:,n] + Wa_b[n] + Ua_b[n]
__global__ void dec_proj_kernel(const float* __restrict__ dh,
                                const float* __restrict__ Wa_w,
                                const float* __restrict__ Wa_b,
                                const float* __restrict__ Ua_b,
                                float* __restrict__ dec_proj) {
    __shared__ float sdh[HH];
    const int b   = blockIdx.x;
    const int nq  = blockIdx.y;           // 0..3
    const int tid = threadIdx.x;          // 256
    for (int i = tid; i < HH; i += 256) sdh[i] = dh[b*HH + i];
    __syncthreads();
    const int n = nq*256 + tid;
    float acc = Wa_b[n] + Ua_b[n];
    for (int k = 0; k < HH; ++k)
        acc = fmaf(sdh[k], Wa_w[(size_t)k*HH + n], acc);
    dec_proj[b*HH + n] = acc;
}

// ---------------- Kernel 2: Ua [K][N] -> B_pre frag-linear split-bf16 image
// (r5/r11-verified 16x16 image)
// B_pre[(nch*NT+kt)*16384 + plane*8192 + f*512 + (c*16+lr)*8 + j]
//   n = nch*256 + f*16 + lr ; k = kt*32 + c*8 + j ; plane 0=hi,1=lo
__global__ void transpose_convert_kernel(const float* __restrict__ Ua,
                                         u16* __restrict__ B_pre) {
    __shared__ u16 shh[64][72], shl[64][72];
    const int nb = blockIdx.x * 64, kb = blockIdx.y * 64;
    const int tid = threadIdx.x;          // 256
    const int kl = tid >> 4, nl4 = (tid & 15) * 4;
    #pragma unroll
    for (int q = 0; q < 4; ++q) {
        const int k = kl + q*16;
        float4 v = *(const float4*)&Ua[(size_t)(kb + k)*HH + nb + nl4];
        float x[4] = {v.x, v.y, v.z, v.w};
        #pragma unroll
        for (int j = 0; j < 4; ++j) {
            u16 hh, ll; split1(x[j], hh, ll);
            shh[k][nl4 + j] = hh; shl[k][nl4 + j] = ll;
        }
    }
    __syncthreads();
    const int nl = tid >> 3, kc8 = (tid & 7) * 8;
    #pragma unroll
    for (int q = 0; q < 2; ++q) {
        const int n = nb + nl + q*32;
        const int kglob = kb + kc8;
        s16x8 hv, lv;
        #pragma unroll
        for (int j = 0; j < 8; ++j) {
            hv[j] = (short)shh[kc8 + j][nl + q*32];
            lv[j] = (short)shl[kc8 + j][nl + q*32];
        }
        const int nchI = n >> 8, fI = (n >> 4) & 15, lrI = n & 15;
        const int ktI = kglob >> 5, cI = (kglob >> 3) & 3;
        const size_t base = (size_t)(nchI*NT + ktI) * BTILE;
        const size_t idxH = base + fI*512 + (cI*16 + lrI)*8;
        *(s16x8*)&B_pre[idxH]        = hv;
        *(s16x8*)&B_pre[idxH + 8192] = lv;
    }
}

// ---------------- Kernel 3: free-run split-bf16 3-product MFMA GEMM, 16x16x32
// r11 schedule + data paths EXACTLY (best measured: 419us, MfmaUtil 43%), but
// 16 waves x 1024 threads, per-wave 64x64 output: acc 128->64 VGPR/lane so
// the kernel fits the 128-VGPR class -> 4 waves/SIMD (was 2). With the same
// one-barrier-per-tile free-run structure, doubled TLP lets LDS reads of some
// waves overlap MFMA of others (m114) instead of phase-locking.
__global__ __launch_bounds__(THREADS, 4)
void gemm_fr_kernel(const float* __restrict__ A,        // enc [M, K] fp32
                    const u16* __restrict__ B_pre,      // frag-linear split image
                    const float* __restrict__ dec_proj, // [B, H] (biases folded)
                    const float* __restrict__ Va_w,     // [H]
                    float* __restrict__ partials)       // [M, 16]
{
    __shared__ __align__(16) u16 AhS[2][BM*BK];   // 2 x 16KB
    __shared__ __align__(16) u16 AlS[2][BM*BK];   // 2 x 16KB
    __shared__ __align__(16) u16 BS[2][BTILE];    // 2 x 32KB

    // XCD-chunked bijective swizzle: 1024 blocks, 128 per XCD;
    // nch fastest -> 4 concurrent blocks share each A panel via L2.
    const int bid = blockIdx.x;
    const int wg  = (bid & 7) * 128 + (bid >> 3);
    const int nch = wg & 3;
    const int mt  = wg >> 2;
    const int m0  = mt * BM, n0 = nch * BN;

    const int tid = threadIdx.x, lane = tid & 63, wid = tid >> 6;
    const int wm = wid >> 2, wn = wid & 3;    // 4 x 4 waves, per-wave 64x64
    const int lr = lane & 15, lk = lane >> 4;

    // A staging: thread -> row=tid>>2 (0..255), quarter=tid&3 (8 fp32 each)
    const int srow = tid >> 2, sq = tid & 3;
    const float* Ab = A + (size_t)(m0 + srow)*HH + sq*8;
    // frag-linear image offset: frag=srow>>4, within: (chunk=sq)*16 + row
    const int awoff = (srow >> 4)*512 + sq*128 + (srow & 15)*8;   // u16 units
    // B staging: wave wid DMAs 2 x 1KB chunks of the 32KB tile image
    const u16* Btile = B_pre + (size_t)nch*NT*BTILE + wid*1024 + lane*8;

    f32x4 acc[4][4];
    #pragma unroll
    for (int i = 0; i < 4; ++i)
        #pragma unroll
        for (int j = 0; j < 4; ++j) acc[i][j] = (f32x4){0.f,0.f,0.f,0.f};

    s16x8  bh[4], bl[4];      // B frags, read once per tile (32 VGPR)
    float4 a0_, a1_;          // A staging regs (8 VGPR)

    auto gloadB = [&](int kt, int db) {
        const u16* src = Btile + (size_t)kt*BTILE;
        u16* dst = &BS[db][wid*1024];
        gload16(src,       dst);
        gload16(src + 512, dst + 512);
    };
    auto loadA = [&](int kt) {
        const float* p = Ab + kt*BK;
        a0_ = *(const float4*)(p + 0);
        a1_ = *(const float4*)(p + 4);
    };
    auto writeA = [&](int db) {
        s16x8 h, l;
        split8v(a0_, a1_, h, l);
        *(s16x8*)&AhS[db][awoff] = h;
        *(s16x8*)&AlS[db][awoff] = l;
    };
    auto readB = [&](int cb) {
        #pragma unroll
        for (int j = 0; j < 4; ++j) {
            const int off = (wn*4 + j)*512 + lane*8;   // contiguous 1KB per frag
            bh[j] = *(const s16x8*)&BS[cb][off];
            bl[j] = *(const s16x8*)&BS[cb][8192 + off];
        }
    };

    // prologue: stage tile 0 into buf 0
    loadA(0);
    gloadB(0, 0);
    writeA(0);
    __syncthreads();
    loadA(1);   // A(1) regs held through iter 0

    for (int j = 0; j < NT; ++j) {
        const int cb = j & 1;
        const bool hn = (j + 1 < NT);
        if (hn) gloadB(j + 1, cb ^ 1);     // B DMA for next tile, issued early
        __builtin_amdgcn_sched_barrier(0);

        readB(cb);
        #pragma unroll
        for (int f = 0; f < 4; ++f) {
            const int o = (wm*4 + f)*512 + lane*8;
            const s16x8 ah = *(const s16x8*)&AhS[cb][o];
            const s16x8 al = *(const s16x8*)&AlS[cb][o];
            __builtin_amdgcn_s_setprio(1);
            #pragma unroll
            for (int q = 0; q < 4; ++q) {
                f32x4 c = acc[f][q];
                c = __builtin_amdgcn_mfma_f32_16x16x32_bf16(ah, bh[q], c, 0, 0, 0);
                c = __builtin_amdgcn_mfma_f32_16x16x32_bf16(ah, bl[q], c, 0, 0, 0);
                c = __builtin_amdgcn_mfma_f32_16x16x32_bf16(al, bh[q], c, 0, 0, 0);
                acc[f][q] = c;
            }
            __builtin_amdgcn_s_setprio(0);
        }
        // staging at END (r11 proven order): writeA's wait targets loads
        // issued a full tile ago (~free); loadA(j+2) gets a full tile to land.
        if (hn) {
            writeA(cb ^ 1);
            loadA(j + 2 < NT ? j + 2 : j + 1);
        }
        __syncthreads();
    }

    // epilogue: rowsum over this wave's 64 n-cols of Va[n]*tanh(C+dp[n])
    // 16x16 C layout (verified): col=lane&15, row=(lane>>4)*4+reg
    const int bidx = m0 >> 11;            // batch index (2048 rows per batch)
    float dp[4], va[4];
    #pragma unroll
    for (int j = 0; j < 4; ++j) {
        const int n = n0 + wn*64 + j*16 + lr;
        dp[j] = dec_proj[bidx*HH + n];
        va[j] = Va_w[n];
    }
    #pragma unroll
    for (int f = 0; f < 4; ++f) {
        #pragma unroll
        for (int r = 0; r < 4; ++r) {
            float s = 0.f;
            #pragma unroll
            for (int j = 0; j < 4; ++j)
                s += va[j] * tanhf(acc[f][j][r] + dp[j]);
            s += __shfl_xor(s, 1, 64);
            s += __shfl_xor(s, 2, 64);
            s += __shfl_xor(s, 4, 64);
            s += __shfl_xor(s, 8, 64);
            if (lr == 0) {
                const int m = m0 + wm*64 + f*16 + lk*4 + r;
                partials[(size_t)m*16 + nch*4 + wn] = s;
            }
        }
    }
}

// ---------------- Kernel 4: sum 16 partials + Va_b, mask, softmax over S
__global__ void softmax_kernel(const float* __restrict__ partials,
                               const int* __restrict__ mask,
                               const float* __restrict__ vb_ptr,
                               float* __restrict__ out)
{
    const int b   = blockIdx.x;
    const int tid = threadIdx.x;   // 256, each handles 8 s-positions
    __shared__ float sred[8];
    const float vb = vb_ptr[0];
    float sc[8];
    float mymax = -INFINITY;
    #pragma unroll
    for (int i = 0; i < 8; ++i) {
        const int s = i*256 + tid;
        const float4* p = (const float4*)&partials[((size_t)b*SS + s)*16];
        const float4 x = p[0], y = p[1], z = p[2], w = p[3];
        float v = (((x.x+x.y)+(x.z+x.w)) + ((y.x+y.y)+(y.z+y.w)))
                + (((z.x+z.y)+(z.z+z.w)) + ((w.x+w.y)+(w.z+w.w))) + vb;
        if (mask[b*SS + s] == 0) v = -1e9f;
        sc[i] = v;
        mymax = fmaxf(mymax, v);
    }
    #pragma unroll
    for (int off = 1; off < 64; off <<= 1)
        mymax = fmaxf(mymax, __shfl_xor(mymax, off, 64));
    const int wave = tid >> 6, lane = tid & 63;
    if (lane == 0) sred[wave] = mymax;
    __syncthreads();
    const float bmax = fmaxf(fmaxf(sred[0], sred[1]), fmaxf(sred[2], sred[3]));
    float ex[8], mysum = 0.f;
    #pragma unroll
    for (int i = 0; i < 8; ++i) {
        ex[i] = __expf(sc[i] - bmax);
        mysum += ex[i];
    }
    #pragma unroll
    for (int off = 1; off < 64; off <<= 1)
        mysum += __shfl_xor(mysum, off, 64);
    if (lane == 0) sred[4 + wave] = mysum;
    __syncthreads();
    const float inv = 1.f / (sred[4] + sred[5] + sred[6] + sred[7]);
    #pragma unroll
    for (int i = 0; i < 8; ++i)
        out[(size_t)b*SS + i*256 + tid] = ex[i] * inv;
}

extern "C" void kernel_launch(void* const* d_in, const int* in_sizes, int n_in,
                              void* d_out, int out_size, void* d_ws, size_t ws_size,
                              hipStream_t stream) {
    const float* dh   = (const float*)d_in[0];
    const float* enc  = (const float*)d_in[1];
    const int*   mask = (const int*)d_in[2];
    const float* Wa_w = (const float*)d_in[3];
    const float* Wa_b = (const float*)d_in[4];
    const float* Ua_w = (const float*)d_in[5];
    const float* Ua_b = (const float*)d_in[6];
    const float* Va_w = (const float*)d_in[7];
    const float* Va_b = (const float*)d_in[8];
    float* out = (float*)d_out;

    float* dec_proj = (float*)d_ws;                       // [B,H]    128 KB
    float* partials = dec_proj + BB*HH;                   // [M,16]   4 MB
    u16*   B_pre    = (u16*)(partials + (size_t)MT*16);   // frag-linear, 4 MB

    dec_proj_kernel<<<dim3(BB, 4), 256, 0, stream>>>(dh, Wa_w, Wa_b, Ua_b, dec_proj);
    transpose_convert_kernel<<<dim3(HH/64, HH/64), 256, 0, stream>>>(Ua_w, B_pre);
    gemm_fr_kernel<<<(MT/BM)*NCH, THREADS, 0, stream>>>(enc, B_pre, dec_proj, Va_w, partials);
    softmax_kernel<<<BB, 256, 0, stream>>>(partials, mask, Va_b, out);
}